// Round 13
// baseline (729.772 us; speedup 1.0000x reference)
//
#include <hip/hip_runtime.h>

#define NN 262144
#define EN 524288
#define HD 128
#define IND 32

#define NT64  (NN/64)      // 4096 64-row tiles
#define GRID_E 768         // k_edge: 3 blocks/CU
#define GRID_G 1024        // k_gru: XCD-paired col-half jobs, no LDS

typedef __attribute__((ext_vector_type(8))) short s16x8;
typedef __attribute__((ext_vector_type(4))) float f32x4;
typedef unsigned short u16;
typedef unsigned int u32;

#define MFMA(a,b,c) __builtin_amdgcn_mfma_f32_16x16x32_bf16(a,b,c,0,0,0)
#define SWZ(p) ((p) ^ ((((p)>>8)&7)<<4))

typedef __attribute__((address_space(1))) void gas_void;
typedef __attribute__((address_space(3))) void las_void;
__device__ __forceinline__ void gload16(const void* g, void* l){
  __builtin_amdgcn_global_load_lds((gas_void*)g, (las_void*)l, 16, 0, 0);
}

__device__ __forceinline__ u16 f2b(float f){          // manual RNE (proven)
  u32 u = __builtin_bit_cast(u32, f);
  u = (u + 0x7fffu + ((u >> 16) & 1u)) >> 16;
  return (u16)u;
}
__device__ __forceinline__ u32 cvtpk(float lo, float hi){   // safe pack (no asm)
  return (u32)f2b(lo) | ((u32)f2b(hi) << 16);
}
__device__ __forceinline__ float b2f(u32 lo16){ return __builtin_bit_cast(float, lo16 << 16); }
__device__ __forceinline__ float rcpf_(float x){ return __builtin_amdgcn_rcpf(x); }
__device__ __forceinline__ float exp2_(float x){ return __builtin_amdgcn_exp2f(x); }
__device__ __forceinline__ float fsig(float x){ return rcpf_(1.f + exp2_(x * -1.442695041f)); }
__device__ __forceinline__ float ftanh(float x){ return fmaf(-2.f, rcpf_(1.f + exp2_(x * 2.885390082f)), 1.f); }

// ---------- weight transform: f32 [K][N] row-major -> bf16 [N][K] col-major ----------
__global__ __launch_bounds__(256) void k_w2bt(const float* __restrict__ W, u16* __restrict__ Wt, int K, int N){
  int idx = blockIdx.x*256 + threadIdx.x;
  if (idx >= K*N) return;
  int n = idx / K, k = idx - n*K;
  Wt[idx] = f2b(W[k*N + n]);
}

// ---------- edge-index dtype probe ----------
__global__ void k_eflag(const int* __restrict__ ei, int* __restrict__ flag){
  int v = ei[threadIdx.x*2 + 1];
  unsigned long long b = __ballot(v != 0);
  if (threadIdx.x == 0) flag[0] = (b == 0ULL) ? 1 : 0;
}
__device__ __forceinline__ int eget(const int* ei, int f, int which, int e){
  return f ? ei[(which*EN + e)*2] : ei[which*EN + e];
}

// ---------- CSR build ----------
__global__ __launch_bounds__(256) void k_count(const int* __restrict__ ei, const int* __restrict__ flag, int* __restrict__ cnt){
  int e = blockIdx.x*256 + threadIdx.x;
  if (e < EN) atomicAdd(&cnt[eget(ei, flag[0], 1, e)], 1);
}
__global__ __launch_bounds__(256) void k_scan1(const int* __restrict__ cnt, int* __restrict__ excl, int* __restrict__ bsum){
  __shared__ int ws[4];
  int i = blockIdx.x*256 + threadIdx.x;
  int v = cnt[i];
  int ln = threadIdx.x & 63;
  int x = v;
  #pragma unroll
  for (int d=1; d<64; d<<=1){ int y = __shfl_up(x, d); if (ln >= d) x += y; }
  if (ln == 63) ws[threadIdx.x>>6] = x;
  __syncthreads();
  int wpre = 0;
  for (int j=0; j<(threadIdx.x>>6); ++j) wpre += ws[j];
  excl[i] = wpre + x - v;
  if (threadIdx.x == 255) bsum[blockIdx.x] = wpre + x;
}
__global__ __launch_bounds__(1024) void k_scan2(int* __restrict__ bsum){
  __shared__ int ws[16];
  int i = threadIdx.x;
  int v = bsum[i];
  int ln = i & 63;
  int x = v;
  #pragma unroll
  for (int d=1; d<64; d<<=1){ int y = __shfl_up(x, d); if (ln >= d) x += y; }
  if (ln == 63) ws[i>>6] = x;
  __syncthreads();
  int wpre = 0;
  for (int j=0; j<(i>>6); ++j) wpre += ws[j];
  bsum[i] = wpre + x - v;
}
__global__ __launch_bounds__(256) void k_scan3(const int* __restrict__ excl, const int* __restrict__ bsum, int* __restrict__ rp, int* __restrict__ cur){
  int i = blockIdx.x*256 + threadIdx.x;
  int v = excl[i] + bsum[blockIdx.x];
  rp[i] = v; cur[i] = v;
  if (i == 0) rp[NN] = EN;
}
__global__ __launch_bounds__(256) void k_fill(const int* __restrict__ ei, const int* __restrict__ flag, int* __restrict__ cur, int* __restrict__ cx){
  int e = blockIdx.x*256 + threadIdx.x;
  if (e >= EN) return;
  int f = flag[0];
  int p = atomicAdd(&cur[eget(ei, f, 1, e)], 1);
  cx[p] = eget(ei, f, 0, e);
}

// ---------- input MLP: h = tanh(x @ W_in + b_in) ----------
__global__ __launch_bounds__(256) void k_input(const float* __restrict__ x, const u16* __restrict__ wt, const float* __restrict__ bias, u16* __restrict__ h){
  const int wv = threadIdx.x >> 6, ln = threadIdx.x & 63;
  const int l15 = ln & 15, lg = ln >> 4;
  const int base = blockIdx.x*128 + wv*32;
  s16x8 a[2];
  #pragma unroll
  for (int rt=0; rt<2; ++rt){
    const float* xp = x + (base + rt*16 + l15)*IND + lg*8;
    float4 v0 = *reinterpret_cast<const float4*>(xp);
    float4 v1 = *reinterpret_cast<const float4*>(xp + 4);
    s16x8 t;
    t[0]=(short)f2b(v0.x); t[1]=(short)f2b(v0.y); t[2]=(short)f2b(v0.z); t[3]=(short)f2b(v0.w);
    t[4]=(short)f2b(v1.x); t[5]=(short)f2b(v1.y); t[6]=(short)f2b(v1.z); t[7]=(short)f2b(v1.w);
    a[rt] = t;
  }
  #pragma unroll
  for (int cg=0; cg<8; ++cg){
    const int col = cg*16 + l15;
    s16x8 bf = *reinterpret_cast<const s16x8*>(wt + col*IND + lg*8);
    float bb = bias[col];
    f32x4 acc0 = {bb,bb,bb,bb}, acc1 = {bb,bb,bb,bb};
    acc0 = MFMA(a[0], bf, acc0);
    acc1 = MFMA(a[1], bf, acc1);
    #pragma unroll
    for (int r=0; r<4; ++r){
      h[(size_t)(base + lg*4 + r)*HD + col]      = f2b(ftanh(acc0[r]));
      h[(size_t)(base + 16 + lg*4 + r)*HD + col] = f2b(ftanh(acc1[r]));
    }
  }
}

// ---------- fused edge MLP: 64-row tiles, persistent, dbuf, 48KB LDS ----------
__global__ __launch_bounds__(512) void k_edge(const u16* __restrict__ h, const u16* __restrict__ wt1, const float* __restrict__ b1,
                                              const u16* __restrict__ wt2, const float* __restrict__ b2, u16* __restrict__ m){
  extern __shared__ __align__(1024) unsigned char lds[];
  const int tid = threadIdx.x, wv = tid >> 6, ln = tid & 63;
  const int l15 = ln & 15, lg = ln >> 4;
  const int col = wv*16 + l15;

  s16x8 B1[4], B2[4];
  #pragma unroll
  for (int kk=0; kk<4; ++kk){
    const int ko = kk*32 + lg*8;
    B1[kk] = *reinterpret_cast<const s16x8*>(wt1 + (size_t)col*HD + ko);
    B2[kk] = *reinterpret_cast<const s16x8*>(wt2 + (size_t)col*HD + ko);
  }
  const float b1s = b1[col], b2s = b2[col];

  {
    const unsigned char* hg = (const unsigned char*)h + (size_t)blockIdx.x*64*256;
    #pragma unroll
    for (int i=0; i<2; ++i){
      int c = wv*2 + i;
      int p = c*1024 + ln*16;
      gload16(hg + SWZ(p), lds + c*1024);
    }
  }
  __syncthreads();

  unsigned char* tl = lds + 32768;
  int t = 0;
  #pragma unroll 1
  for (int tt = blockIdx.x; tt < NT64; tt += GRID_E, ++t){
    if (tt + GRID_E < NT64){
      const unsigned char* hg = (const unsigned char*)h + (size_t)(tt+GRID_E)*64*256;
      unsigned char* dst = lds + ((t+1)&1)*16384;
      #pragma unroll
      for (int i=0; i<2; ++i){
        int c = wv*2 + i;
        int p = c*1024 + ln*16;
        gload16(hg + SWZ(p), dst + c*1024);
      }
    }
    const unsigned char* hl = lds + (t&1)*16384;
    for (int rt=0; rt<4; ++rt){
      s16x8 a[4];
      #pragma unroll
      for (int kk=0; kk<4; ++kk){
        int row = rt*16 + l15;
        int p = row*256 + (((kk*4+lg) ^ (row&7))<<4);
        a[kk] = *reinterpret_cast<const s16x8*>(hl + p);
      }
      f32x4 acc = {b1s,b1s,b1s,b1s};
      __builtin_amdgcn_s_setprio(1);
      #pragma unroll
      for (int kk=0; kk<4; ++kk) acc = MFMA(a[kk], B1[kk], acc);
      __builtin_amdgcn_s_setprio(0);
      #pragma unroll
      for (int r=0; r<4; ++r){
        int row = rt*16 + lg*4 + r;
        int tb = row*256 + ((((col*2)>>4) ^ (row&7))<<4) + ((col&7)*2);
        *reinterpret_cast<u16*>(tl + tb) = f2b(ftanh(acc[r]));
      }
    }
    __syncthreads();
    for (int rt=0; rt<4; ++rt){
      s16x8 a[4];
      #pragma unroll
      for (int kk=0; kk<4; ++kk){
        int row = rt*16 + l15;
        int p = row*256 + (((kk*4+lg) ^ (row&7))<<4);
        a[kk] = *reinterpret_cast<const s16x8*>(tl + p);
      }
      f32x4 acc = {b2s,b2s,b2s,b2s};
      __builtin_amdgcn_s_setprio(1);
      #pragma unroll
      for (int kk=0; kk<4; ++kk) acc = MFMA(a[kk], B2[kk], acc);
      __builtin_amdgcn_s_setprio(0);
      u16* mp = m + (size_t)(tt*64 + rt*16 + lg*4)*HD + col;
      mp[0]    = f2b(acc[0]);
      mp[HD]   = f2b(acc[1]);
      mp[2*HD] = f2b(acc[2]);
      mp[3*HD] = f2b(acc[3]);
    }
    __syncthreads();
  }
}

// ---------- aggregation: half-wave (32 lanes) per node, uint2 row reads ----------
__global__ __launch_bounds__(256) void k_agg(const u16* __restrict__ m, const int* __restrict__ rp, const int* __restrict__ cx, u16* __restrict__ magg){
  const int sub = threadIdx.x >> 5, l32 = threadIdx.x & 31;
  const int n = blockIdx.x*8 + sub;
  int s0 = rp[n], s1 = rp[n+1];
  float a0=0.f, a1=0.f, a2=0.f, a3=0.f;
  int p = s0;
  for (; p + 2 <= s1; p += 2){
    int na = cx[p], nb = cx[p+1];
    uint2 va = *reinterpret_cast<const uint2*>(m + (size_t)na*HD + l32*4);
    uint2 vb = *reinterpret_cast<const uint2*>(m + (size_t)nb*HD + l32*4);
    a0 += b2f(va.x & 0xffffu) + b2f(vb.x & 0xffffu);
    a1 += b2f(va.x >> 16)     + b2f(vb.x >> 16);
    a2 += b2f(va.y & 0xffffu) + b2f(vb.y & 0xffffu);
    a3 += b2f(va.y >> 16)     + b2f(vb.y >> 16);
  }
  if (p < s1){
    int na = cx[p];
    uint2 va = *reinterpret_cast<const uint2*>(m + (size_t)na*HD + l32*4);
    a0 += b2f(va.x & 0xffffu); a1 += b2f(va.x >> 16);
    a2 += b2f(va.y & 0xffffu); a3 += b2f(va.y >> 16);
  }
  int deg = s1 - s0;
  float inv = rcpf_((float)(deg > 0 ? deg : 1));
  uint2 o;
  o.x = cvtpk(a0*inv, a1*inv);
  o.y = cvtpk(a2*inv, a3*inv);
  *reinterpret_cast<uint2*>(magg + (size_t)n*HD + l32*4) = o;
}

// ---------- fused GRU v13: direct-L2 A-fragments, NO LDS/barriers, FIXED pipeline ----------
// Proven round-5 interleave: LOAD(rt,X); MFMAS(X); EPI(rt-1,Y) — no hld clobber.
__global__ __launch_bounds__(256, 2) void k_gru(const u16* __restrict__ magg, const u16* __restrict__ hin, u16* __restrict__ hout,
    const u16* __restrict__ wtih, const float* __restrict__ bih,
    const u16* __restrict__ wthh, const float* __restrict__ bhh){
  const int tid = threadIdx.x, wv = tid >> 6, ln = tid & 63;
  const int l15 = ln & 15, lg = ln >> 4;
  const int xcd = blockIdx.x & 7;
  const int q   = blockIdx.x >> 3;          // 0..127
  const int ch  = q & 1;                    // col-half (block-constant)
  const int p0  = (q >> 1)*8 + xcd;         // first row-tile, 0..511
  const int col = ch*64 + wv*16 + l15;
  const int ce = col & ~1;

  s16x8 B[6][4];
  #pragma unroll
  for (int kk=0; kk<4; ++kk){
    const int ko = kk*32 + lg*8;
    B[0][kk] = *reinterpret_cast<const s16x8*>(wtih + (size_t)(col       )*HD + ko);
    B[1][kk] = *reinterpret_cast<const s16x8*>(wtih + (size_t)(col +   HD)*HD + ko);
    B[2][kk] = *reinterpret_cast<const s16x8*>(wtih + (size_t)(col + 2*HD)*HD + ko);
    B[3][kk] = *reinterpret_cast<const s16x8*>(wthh + (size_t)(col       )*HD + ko);
    B[4][kk] = *reinterpret_cast<const s16x8*>(wthh + (size_t)(col +   HD)*HD + ko);
    B[5][kk] = *reinterpret_cast<const s16x8*>(wthh + (size_t)(col + 2*HD)*HD + ko);
  }
  const float brz = bih[col] + bhh[col];
  const float bzz = bih[col+HD] + bhh[col+HD];
  const float bin_ = bih[col+2*HD], bhn_ = bhh[col+2*HD];

#define LOADG(rt, amg, ahh, hld) { \
    const size_t rb_ = (size_t)(base + (rt)*16 + l15)*HD + lg*8; \
    _Pragma("unroll") \
    for (int kk=0; kk<4; ++kk){ \
      amg[kk] = *reinterpret_cast<const s16x8*>(magg + rb_ + kk*32); \
      ahh[kk] = *reinterpret_cast<const s16x8*>(hin  + rb_ + kk*32); } \
    _Pragma("unroll") \
    for (int r_=0; r_<4; ++r_){ \
      hld[r_] = *reinterpret_cast<const u32*>(hin + (size_t)(base + (rt)*16 + lg*4 + r_)*HD + ce); } }

#define MFMAS(amg, ahh, aR, aZ, aN, aH) { \
    aR = (f32x4){brz,brz,brz,brz}; aZ = (f32x4){bzz,bzz,bzz,bzz}; \
    aN = (f32x4){bin_,bin_,bin_,bin_}; aH = (f32x4){bhn_,bhn_,bhn_,bhn_}; \
    __builtin_amdgcn_s_setprio(1); \
    _Pragma("unroll") \
    for (int kk=0; kk<4; ++kk){ \
      aR = MFMA(amg[kk], B[0][kk], aR); \
      aZ = MFMA(amg[kk], B[1][kk], aZ); \
      aN = MFMA(amg[kk], B[2][kk], aN); \
      aH = MFMA(ahh[kk], B[5][kk], aH); \
      aR = MFMA(ahh[kk], B[3][kk], aR); \
      aZ = MFMA(ahh[kk], B[4][kk], aZ); } \
    __builtin_amdgcn_s_setprio(0); }

#define EPI(rt, aR, aZ, aN, aH, hld) { \
    u16* hp_ = hout + (size_t)(base + (rt)*16 + lg*4)*HD + col; \
    _Pragma("unroll") \
    for (int r_=0; r_<4; ++r_){ \
      float hold_ = __builtin_bit_cast(float, (col&1) ? (hld[r_] & 0xffff0000u) : (hld[r_] << 16)); \
      float rg_ = fsig(aR[r_]); \
      float zg_ = fsig(aZ[r_]); \
      float ng_ = ftanh(aN[r_] + rg_*aH[r_]); \
      hp_[r_*HD] = f2b(ng_ + zg_*(hold_ - ng_)); } }

  #pragma unroll 1
  for (int rowt = p0; rowt < NT64; rowt += 512){
    const int base = rowt*64;

    s16x8 amgA[4], ahhA[4], amgB[4], ahhB[4];
    u32 hldA[4], hldB[4];
    f32x4 rA, zA, nA, hA, rB, zB, nB, hB;

    // proven interleave: LOAD(rt,X); MFMAS(X); EPI(rt-1,Y)
    LOADG(0, amgA, ahhA, hldA); MFMAS(amgA, ahhA, rA, zA, nA, hA);
    LOADG(1, amgB, ahhB, hldB); MFMAS(amgB, ahhB, rB, zB, nB, hB); EPI(0, rA, zA, nA, hA, hldA);
    LOADG(2, amgA, ahhA, hldA); MFMAS(amgA, ahhA, rA, zA, nA, hA); EPI(1, rB, zB, nB, hB, hldB);
    LOADG(3, amgB, ahhB, hldB); MFMAS(amgB, ahhB, rB, zB, nB, hB); EPI(2, rA, zA, nA, hA, hldA);
    EPI(3, rB, zB, nB, hB, hldB);
  }
#undef LOADG
#undef MFMAS
#undef EPI
}

// ---------- output head ----------
__global__ __launch_bounds__(256) void k_out(const u16* __restrict__ h, const float* __restrict__ wo, const float* __restrict__ bo, float* __restrict__ out){
  const int wv = threadIdx.x >> 6, ln = threadIdx.x & 63;
  const int n = (blockIdx.x*4 + wv)*4 + (ln >> 4);
  const int kc = (ln & 15)*8;
  uint4 v = *reinterpret_cast<const uint4*>(h + (size_t)n*HD + kc);
  float4 w0 = *reinterpret_cast<const float4*>(wo + kc);
  float4 w1 = *reinterpret_cast<const float4*>(wo + kc + 4);
  float s = b2f(v.x & 0xffffu)*w0.x + b2f(v.x >> 16)*w0.y + b2f(v.y & 0xffffu)*w0.z + b2f(v.y >> 16)*w0.w
          + b2f(v.z & 0xffffu)*w1.x + b2f(v.z >> 16)*w1.y + b2f(v.w & 0xffffu)*w1.z + b2f(v.w >> 16)*w1.w;
  #pragma unroll
  for (int d=1; d<16; d<<=1) s += __shfl_xor(s, d, 16);
  if ((ln & 15) == 0) out[n] = s + bo[0];
}

// ---------- workspace layout ----------
#define AL256(x) ((((size_t)(x)) + 255) & ~(size_t)255)
static const size_t SZ_STATE = (size_t)NN*HD*2;
static const size_t OFF_HA   = 0;                       // h ping buffer
static const size_t OFF_HB   = OFF_HA + SZ_STATE;       // h pong buffer / m buffer
static const size_t OFF_MAGG = OFF_HB + SZ_STATE;
static const size_t OFF_RP   = OFF_MAGG + SZ_STATE;
static const size_t OFF_CUR  = OFF_RP + AL256((size_t)(NN+1)*4);
static const size_t OFF_CNT  = OFF_CUR + (size_t)NN*4;
static const size_t OFF_EXCL = OFF_CNT + (size_t)NN*4;
static const size_t OFF_BSUM = OFF_EXCL + (size_t)NN*4;
static const size_t OFF_CX   = OFF_BSUM + AL256(1024*4);
static const size_t OFF_FLAG = OFF_CX + (size_t)EN*4;
static const size_t OFF_WTIN = OFF_FLAG + 256;
static const size_t OFF_WTE1 = OFF_WTIN + AL256((size_t)IND*HD*2);
static const size_t OFF_WTE2 = OFF_WTE1 + AL256((size_t)HD*HD*2);
static const size_t OFF_WTIH = OFF_WTE2 + AL256((size_t)HD*HD*2);
static const size_t OFF_WTHH = OFF_WTIH + AL256((size_t)HD*3*HD*2);

extern "C" void kernel_launch(void* const* d_in, const int* in_sizes, int n_in,
                              void* d_out, int out_size, void* d_ws, size_t ws_size,
                              hipStream_t stream){
  const float* x    = (const float*)d_in[0];
  const int*   ei   = (const int*)d_in[1];
  const float* W_in = (const float*)d_in[2];  const float* b_in = (const float*)d_in[3];
  const float* W_e1 = (const float*)d_in[4];  const float* b_e1 = (const float*)d_in[5];
  const float* W_e2 = (const float*)d_in[6];  const float* b_e2 = (const float*)d_in[7];
  const float* W_ih = (const float*)d_in[8];  const float* b_ih = (const float*)d_in[9];
  const float* W_hh = (const float*)d_in[10]; const float* b_hh = (const float*)d_in[11];
  const float* W_out= (const float*)d_in[12]; const float* b_out= (const float*)d_in[13];
  float* out = (float*)d_out;

  char* ws = (char*)d_ws;
  u16* hA   = (u16*)(ws + OFF_HA);
  u16* hB   = (u16*)(ws + OFF_HB);
  u16* magg = (u16*)(ws + OFF_MAGG);
  int* rp   = (int*)(ws + OFF_RP);
  int* cur  = (int*)(ws + OFF_CUR);
  int* cnt  = (int*)(ws + OFF_CNT);
  int* excl = (int*)(ws + OFF_EXCL);
  int* bsum = (int*)(ws + OFF_BSUM);
  int* cx   = (int*)(ws + OFF_CX);
  int* flag = (int*)(ws + OFF_FLAG);
  u16* wtin = (u16*)(ws + OFF_WTIN);
  u16* wte1 = (u16*)(ws + OFF_WTE1);
  u16* wte2 = (u16*)(ws + OFF_WTE2);
  u16* wtih = (u16*)(ws + OFF_WTIH);
  u16* wthh = (u16*)(ws + OFF_WTHH);

  hipFuncSetAttribute((const void*)k_edge, hipFuncAttributeMaxDynamicSharedMemorySize, 49152);

  hipMemsetAsync(cnt, 0, (size_t)NN*4, stream);

  k_w2bt<<<(IND*HD + 255)/256, 256, 0, stream>>>(W_in, wtin, IND, HD);
  k_w2bt<<<(HD*HD + 255)/256, 256, 0, stream>>>(W_e1, wte1, HD, HD);
  k_w2bt<<<(HD*HD + 255)/256, 256, 0, stream>>>(W_e2, wte2, HD, HD);
  k_w2bt<<<(HD*3*HD + 255)/256, 256, 0, stream>>>(W_ih, wtih, HD, 3*HD);
  k_w2bt<<<(HD*3*HD + 255)/256, 256, 0, stream>>>(W_hh, wthh, HD, 3*HD);

  k_eflag<<<1, 64, 0, stream>>>(ei, flag);
  k_count<<<EN/256, 256, 0, stream>>>(ei, flag, cnt);
  k_scan1<<<NN/256, 256, 0, stream>>>(cnt, excl, bsum);
  k_scan2<<<1, 1024, 0, stream>>>(bsum);
  k_scan3<<<NN/256, 256, 0, stream>>>(excl, bsum, rp, cur);
  k_fill<<<EN/256, 256, 0, stream>>>(ei, flag, cur, cx);

  k_input<<<NN/128, 256, 0, stream>>>(x, wtin, b_in, hA);

  // ping-pong: h state alternates hA -> hB -> hA -> hB; m shares the inactive buffer
  for (int it=0; it<3; ++it){
    u16* hin  = (it & 1) ? hB : hA;
    u16* hout = (it & 1) ? hA : hB;   // also serves as the m buffer this iteration
    k_edge<<<GRID_E, 512, 49152, stream>>>(hin, wte1, b_e1, wte2, b_e2, hout);
    k_agg<<<NN/8, 256, 0, stream>>>(hout, rp, cx, magg);
    k_gru<<<GRID_G, 256, 0, stream>>>(magg, hin, hout, wtih, b_ih, wthh, b_hh);
  }
  k_out<<<NN/16, 256, 0, stream>>>(hB, W_out, b_out, out);
}

// Round 14
// 524.682 us; speedup vs baseline: 1.3909x; 1.3909x over previous
//
#include <hip/hip_runtime.h>

#define NN 262144
#define EN 524288
#define HD 128
#define IND 32

#define NT64  (NN/64)      // 4096 64-row tiles
#define GRID_E 768         // k_edge: 3 blocks/CU
#define GRID_G 512         // k_gru: 256 XCD-paired (rowt-seq, col-half) blocks x2

typedef __attribute__((ext_vector_type(8))) short s16x8;
typedef __attribute__((ext_vector_type(4))) float f32x4;
typedef unsigned short u16;
typedef unsigned int u32;

#define MFMA(a,b,c) __builtin_amdgcn_mfma_f32_16x16x32_bf16(a,b,c,0,0,0)
#define SWZ(p) ((p) ^ ((((p)>>8)&7)<<4))

typedef __attribute__((address_space(1))) void gas_void;
typedef __attribute__((address_space(3))) void las_void;
__device__ __forceinline__ void gload16(const void* g, void* l){
  __builtin_amdgcn_global_load_lds((gas_void*)g, (las_void*)l, 16, 0, 0);
}

__device__ __forceinline__ u16 f2b(float f){          // manual RNE (proven)
  u32 u = __builtin_bit_cast(u32, f);
  u = (u + 0x7fffu + ((u >> 16) & 1u)) >> 16;
  return (u16)u;
}
__device__ __forceinline__ u32 cvtpk(float lo, float hi){   // safe pack (no asm)
  return (u32)f2b(lo) | ((u32)f2b(hi) << 16);
}
__device__ __forceinline__ float b2f(u32 lo16){ return __builtin_bit_cast(float, lo16 << 16); }
__device__ __forceinline__ float rcpf_(float x){ return __builtin_amdgcn_rcpf(x); }
__device__ __forceinline__ float exp2_(float x){ return __builtin_amdgcn_exp2f(x); }
__device__ __forceinline__ float fsig(float x){ return rcpf_(1.f + exp2_(x * -1.442695041f)); }
__device__ __forceinline__ float ftanh(float x){ return fmaf(-2.f, rcpf_(1.f + exp2_(x * 2.885390082f)), 1.f); }

// ---------- weight transform: f32 [K][N] row-major -> bf16 [N][K] col-major ----------
__global__ __launch_bounds__(256) void k_w2bt(const float* __restrict__ W, u16* __restrict__ Wt, int K, int N){
  int idx = blockIdx.x*256 + threadIdx.x;
  if (idx >= K*N) return;
  int n = idx / K, k = idx - n*K;
  Wt[idx] = f2b(W[k*N + n]);
}

// ---------- edge-index dtype probe ----------
__global__ void k_eflag(const int* __restrict__ ei, int* __restrict__ flag){
  int v = ei[threadIdx.x*2 + 1];
  unsigned long long b = __ballot(v != 0);
  if (threadIdx.x == 0) flag[0] = (b == 0ULL) ? 1 : 0;
}
__device__ __forceinline__ int eget(const int* ei, int f, int which, int e){
  return f ? ei[(which*EN + e)*2] : ei[which*EN + e];
}

// ---------- CSR build ----------
__global__ __launch_bounds__(256) void k_count(const int* __restrict__ ei, const int* __restrict__ flag, int* __restrict__ cnt){
  int e = blockIdx.x*256 + threadIdx.x;
  if (e < EN) atomicAdd(&cnt[eget(ei, flag[0], 1, e)], 1);
}
__global__ __launch_bounds__(256) void k_scan1(const int* __restrict__ cnt, int* __restrict__ excl, int* __restrict__ bsum){
  __shared__ int ws[4];
  int i = blockIdx.x*256 + threadIdx.x;
  int v = cnt[i];
  int ln = threadIdx.x & 63;
  int x = v;
  #pragma unroll
  for (int d=1; d<64; d<<=1){ int y = __shfl_up(x, d); if (ln >= d) x += y; }
  if (ln == 63) ws[threadIdx.x>>6] = x;
  __syncthreads();
  int wpre = 0;
  for (int j=0; j<(threadIdx.x>>6); ++j) wpre += ws[j];
  excl[i] = wpre + x - v;
  if (threadIdx.x == 255) bsum[blockIdx.x] = wpre + x;
}
__global__ __launch_bounds__(1024) void k_scan2(int* __restrict__ bsum){
  __shared__ int ws[16];
  int i = threadIdx.x;
  int v = bsum[i];
  int ln = i & 63;
  int x = v;
  #pragma unroll
  for (int d=1; d<64; d<<=1){ int y = __shfl_up(x, d); if (ln >= d) x += y; }
  if (ln == 63) ws[i>>6] = x;
  __syncthreads();
  int wpre = 0;
  for (int j=0; j<(i>>6); ++j) wpre += ws[j];
  bsum[i] = wpre + x - v;
}
__global__ __launch_bounds__(256) void k_scan3(const int* __restrict__ excl, const int* __restrict__ bsum, int* __restrict__ rp, int* __restrict__ cur){
  int i = blockIdx.x*256 + threadIdx.x;
  int v = excl[i] + bsum[blockIdx.x];
  rp[i] = v; cur[i] = v;
  if (i == 0) rp[NN] = EN;
}
__global__ __launch_bounds__(256) void k_fill(const int* __restrict__ ei, const int* __restrict__ flag, int* __restrict__ cur, int* __restrict__ cx){
  int e = blockIdx.x*256 + threadIdx.x;
  if (e >= EN) return;
  int f = flag[0];
  int p = atomicAdd(&cur[eget(ei, f, 1, e)], 1);
  cx[p] = eget(ei, f, 0, e);
}

// ---------- input MLP: h = tanh(x @ W_in + b_in) ----------
__global__ __launch_bounds__(256) void k_input(const float* __restrict__ x, const u16* __restrict__ wt, const float* __restrict__ bias, u16* __restrict__ h){
  const int wv = threadIdx.x >> 6, ln = threadIdx.x & 63;
  const int l15 = ln & 15, lg = ln >> 4;
  const int base = blockIdx.x*128 + wv*32;
  s16x8 a[2];
  #pragma unroll
  for (int rt=0; rt<2; ++rt){
    const float* xp = x + (base + rt*16 + l15)*IND + lg*8;
    float4 v0 = *reinterpret_cast<const float4*>(xp);
    float4 v1 = *reinterpret_cast<const float4*>(xp + 4);
    s16x8 t;
    t[0]=(short)f2b(v0.x); t[1]=(short)f2b(v0.y); t[2]=(short)f2b(v0.z); t[3]=(short)f2b(v0.w);
    t[4]=(short)f2b(v1.x); t[5]=(short)f2b(v1.y); t[6]=(short)f2b(v1.z); t[7]=(short)f2b(v1.w);
    a[rt] = t;
  }
  #pragma unroll
  for (int cg=0; cg<8; ++cg){
    const int col = cg*16 + l15;
    s16x8 bf = *reinterpret_cast<const s16x8*>(wt + col*IND + lg*8);
    float bb = bias[col];
    f32x4 acc0 = {bb,bb,bb,bb}, acc1 = {bb,bb,bb,bb};
    acc0 = MFMA(a[0], bf, acc0);
    acc1 = MFMA(a[1], bf, acc1);
    #pragma unroll
    for (int r=0; r<4; ++r){
      h[(size_t)(base + lg*4 + r)*HD + col]      = f2b(ftanh(acc0[r]));
      h[(size_t)(base + 16 + lg*4 + r)*HD + col] = f2b(ftanh(acc1[r]));
    }
  }
}

// ---------- fused edge MLP: 64-row tiles, persistent, dbuf, 48KB LDS ----------
__global__ __launch_bounds__(512) void k_edge(const u16* __restrict__ h, const u16* __restrict__ wt1, const float* __restrict__ b1,
                                              const u16* __restrict__ wt2, const float* __restrict__ b2, u16* __restrict__ m){
  extern __shared__ __align__(1024) unsigned char lds[];
  const int tid = threadIdx.x, wv = tid >> 6, ln = tid & 63;
  const int l15 = ln & 15, lg = ln >> 4;
  const int col = wv*16 + l15;

  s16x8 B1[4], B2[4];
  #pragma unroll
  for (int kk=0; kk<4; ++kk){
    const int ko = kk*32 + lg*8;
    B1[kk] = *reinterpret_cast<const s16x8*>(wt1 + (size_t)col*HD + ko);
    B2[kk] = *reinterpret_cast<const s16x8*>(wt2 + (size_t)col*HD + ko);
  }
  const float b1s = b1[col], b2s = b2[col];

  {
    const unsigned char* hg = (const unsigned char*)h + (size_t)blockIdx.x*64*256;
    #pragma unroll
    for (int i=0; i<2; ++i){
      int c = wv*2 + i;
      int p = c*1024 + ln*16;
      gload16(hg + SWZ(p), lds + c*1024);
    }
  }
  __syncthreads();

  unsigned char* tl = lds + 32768;
  int t = 0;
  #pragma unroll 1
  for (int tt = blockIdx.x; tt < NT64; tt += GRID_E, ++t){
    if (tt + GRID_E < NT64){
      const unsigned char* hg = (const unsigned char*)h + (size_t)(tt+GRID_E)*64*256;
      unsigned char* dst = lds + ((t+1)&1)*16384;
      #pragma unroll
      for (int i=0; i<2; ++i){
        int c = wv*2 + i;
        int p = c*1024 + ln*16;
        gload16(hg + SWZ(p), dst + c*1024);
      }
    }
    const unsigned char* hl = lds + (t&1)*16384;
    for (int rt=0; rt<4; ++rt){
      s16x8 a[4];
      #pragma unroll
      for (int kk=0; kk<4; ++kk){
        int row = rt*16 + l15;
        int p = row*256 + (((kk*4+lg) ^ (row&7))<<4);
        a[kk] = *reinterpret_cast<const s16x8*>(hl + p);
      }
      f32x4 acc = {b1s,b1s,b1s,b1s};
      __builtin_amdgcn_s_setprio(1);
      #pragma unroll
      for (int kk=0; kk<4; ++kk) acc = MFMA(a[kk], B1[kk], acc);
      __builtin_amdgcn_s_setprio(0);
      #pragma unroll
      for (int r=0; r<4; ++r){
        int row = rt*16 + lg*4 + r;
        int tb = row*256 + ((((col*2)>>4) ^ (row&7))<<4) + ((col&7)*2);
        *reinterpret_cast<u16*>(tl + tb) = f2b(ftanh(acc[r]));
      }
    }
    __syncthreads();
    for (int rt=0; rt<4; ++rt){
      s16x8 a[4];
      #pragma unroll
      for (int kk=0; kk<4; ++kk){
        int row = rt*16 + l15;
        int p = row*256 + (((kk*4+lg) ^ (row&7))<<4);
        a[kk] = *reinterpret_cast<const s16x8*>(tl + p);
      }
      f32x4 acc = {b2s,b2s,b2s,b2s};
      __builtin_amdgcn_s_setprio(1);
      #pragma unroll
      for (int kk=0; kk<4; ++kk) acc = MFMA(a[kk], B2[kk], acc);
      __builtin_amdgcn_s_setprio(0);
      u16* mp = m + (size_t)(tt*64 + rt*16 + lg*4)*HD + col;
      mp[0]    = f2b(acc[0]);
      mp[HD]   = f2b(acc[1]);
      mp[2*HD] = f2b(acc[2]);
      mp[3*HD] = f2b(acc[3]);
    }
    __syncthreads();
  }
}

// ---------- aggregation: half-wave (32 lanes) per node, uint2 row reads ----------
__global__ __launch_bounds__(256) void k_agg(const u16* __restrict__ m, const int* __restrict__ rp, const int* __restrict__ cx, u16* __restrict__ magg){
  const int sub = threadIdx.x >> 5, l32 = threadIdx.x & 31;
  const int n = blockIdx.x*8 + sub;
  int s0 = rp[n], s1 = rp[n+1];
  float a0=0.f, a1=0.f, a2=0.f, a3=0.f;
  int p = s0;
  for (; p + 2 <= s1; p += 2){
    int na = cx[p], nb = cx[p+1];
    uint2 va = *reinterpret_cast<const uint2*>(m + (size_t)na*HD + l32*4);
    uint2 vb = *reinterpret_cast<const uint2*>(m + (size_t)nb*HD + l32*4);
    a0 += b2f(va.x & 0xffffu) + b2f(vb.x & 0xffffu);
    a1 += b2f(va.x >> 16)     + b2f(vb.x >> 16);
    a2 += b2f(va.y & 0xffffu) + b2f(vb.y & 0xffffu);
    a3 += b2f(va.y >> 16)     + b2f(vb.y >> 16);
  }
  if (p < s1){
    int na = cx[p];
    uint2 va = *reinterpret_cast<const uint2*>(m + (size_t)na*HD + l32*4);
    a0 += b2f(va.x & 0xffffu); a1 += b2f(va.x >> 16);
    a2 += b2f(va.y & 0xffffu); a3 += b2f(va.y >> 16);
  }
  int deg = s1 - s0;
  float inv = rcpf_((float)(deg > 0 ? deg : 1));
  uint2 o;
  o.x = cvtpk(a0*inv, a1*inv);
  o.y = cvtpk(a2*inv, a3*inv);
  *reinterpret_cast<uint2*>(magg + (size_t)n*HD + l32*4) = o;
}

// ---------- fused GRU v14: col-split + ping-pong h, XCD-paired + double-buffered ----------
// pair = same rowt sequence for both col-half blocks, same XCD (bids differ by 8)
// dyn LDS 64KB: buf b at b*32K: [0,16K)=magg tile, [16K,32K)=hin tile
__global__ __launch_bounds__(256, 2) void k_gru(const u16* __restrict__ magg, const u16* __restrict__ hin, u16* __restrict__ hout,
    const u16* __restrict__ wtih, const float* __restrict__ bih,
    const u16* __restrict__ wthh, const float* __restrict__ bhh){
  extern __shared__ __align__(1024) unsigned char lds[];
  const int tid = threadIdx.x, wv = tid >> 6, ln = tid & 63;
  const int l15 = ln & 15, lg = ln >> 4;
  const int xcd = blockIdx.x & 7;
  const int q   = blockIdx.x >> 3;          // 0..63
  const int ch  = q & 1;                    // col-half (block-constant)
  const int pair = (q >> 1)*8 + xcd;        // 0..255; both halves share rowt seq
  const int col = ch*64 + wv*16 + l15;
  const int ce = col & ~1;

  s16x8 B[6][4];
  #pragma unroll
  for (int kk=0; kk<4; ++kk){
    const int ko = kk*32 + lg*8;
    B[0][kk] = *reinterpret_cast<const s16x8*>(wtih + (size_t)(col       )*HD + ko);
    B[1][kk] = *reinterpret_cast<const s16x8*>(wtih + (size_t)(col +   HD)*HD + ko);
    B[2][kk] = *reinterpret_cast<const s16x8*>(wtih + (size_t)(col + 2*HD)*HD + ko);
    B[3][kk] = *reinterpret_cast<const s16x8*>(wthh + (size_t)(col       )*HD + ko);
    B[4][kk] = *reinterpret_cast<const s16x8*>(wthh + (size_t)(col +   HD)*HD + ko);
    B[5][kk] = *reinterpret_cast<const s16x8*>(wthh + (size_t)(col + 2*HD)*HD + ko);
  }
  const float brz = bih[col] + bhh[col];
  const float bzz = bih[col+HD] + bhh[col+HD];
  const float bin_ = bih[col+2*HD], bhn_ = bhh[col+2*HD];

  // prologue: stage first tile (rowt = pair) into buf 0
  {
    const size_t rbase = (size_t)pair*64*256;
    const unsigned char* mg = (const unsigned char*)magg + rbase;
    const unsigned char* hg = (const unsigned char*)hin  + rbase;
    #pragma unroll
    for (int i=0; i<8; ++i){
      int c = wv*8 + i;
      int p = (c & 15)*1024 + ln*16;
      gload16((c < 16 ? mg : hg) + SWZ(p), lds + c*1024);
    }
  }
  __syncthreads();

#define LOADA(rt, amg, ahh, hld) { \
    const int row_ = (rt)*16 + l15; \
    _Pragma("unroll") \
    for (int kk=0; kk<4; ++kk){ \
      int p_ = row_*256 + (((kk*4+lg) ^ (row_&7))<<4); \
      amg[kk] = *reinterpret_cast<const s16x8*>(mgl + p_); \
      ahh[kk] = *reinterpret_cast<const s16x8*>(hl + p_); } \
    _Pragma("unroll") \
    for (int r_=0; r_<4; ++r_){ \
      int hrow_ = (rt)*16 + lg*4 + r_; \
      int hb_ = hrow_*256 + ((((ce*2)>>4) ^ (hrow_&7))<<4) + ((ce&7)*2); \
      hld[r_] = *reinterpret_cast<const u32*>(hl + hb_); } }

#define MFMAS(amg, ahh, aR, aZ, aN, aH) { \
    aR = (f32x4){brz,brz,brz,brz}; aZ = (f32x4){bzz,bzz,bzz,bzz}; \
    aN = (f32x4){bin_,bin_,bin_,bin_}; aH = (f32x4){bhn_,bhn_,bhn_,bhn_}; \
    __builtin_amdgcn_s_setprio(1); \
    _Pragma("unroll") \
    for (int kk=0; kk<4; ++kk){ \
      aR = MFMA(amg[kk], B[0][kk], aR); \
      aZ = MFMA(amg[kk], B[1][kk], aZ); \
      aN = MFMA(amg[kk], B[2][kk], aN); \
      aH = MFMA(ahh[kk], B[5][kk], aH); \
      aR = MFMA(ahh[kk], B[3][kk], aR); \
      aZ = MFMA(ahh[kk], B[4][kk], aZ); } \
    __builtin_amdgcn_s_setprio(0); }

#define EPI(rt, aR, aZ, aN, aH, hld) { \
    u16* hp_ = hout + (size_t)(rowt*64 + (rt)*16 + lg*4)*HD + col; \
    _Pragma("unroll") \
    for (int r_=0; r_<4; ++r_){ \
      float hold_ = __builtin_bit_cast(float, (col&1) ? (hld[r_] & 0xffff0000u) : (hld[r_] << 16)); \
      float rg_ = fsig(aR[r_]); \
      float zg_ = fsig(aZ[r_]); \
      float ng_ = ftanh(aN[r_] + rg_*aH[r_]); \
      hp_[r_*HD] = f2b(ng_ + zg_*(hold_ - ng_)); } }

  int t = 0;
  #pragma unroll 1
  for (int rowt = pair; rowt < NT64; rowt += 256, ++t){
    // prefetch next tile into the other buffer (drained by end barrier, under compute)
    if (rowt + 256 < NT64){
      const size_t rbase = (size_t)(rowt + 256)*64*256;
      const unsigned char* mg = (const unsigned char*)magg + rbase;
      const unsigned char* hg = (const unsigned char*)hin  + rbase;
      unsigned char* dst = lds + ((t+1)&1)*32768;
      #pragma unroll
      for (int i=0; i<8; ++i){
        int c = wv*8 + i;
        int p = (c & 15)*1024 + ln*16;
        gload16((c < 16 ? mg : hg) + SWZ(p), dst + c*1024);
      }
    }
    const unsigned char* mgl = lds + (t&1)*32768;
    const unsigned char* hl  = mgl + 16384;

    s16x8 amgA[4], ahhA[4], amgB[4], ahhB[4];
    u32 hldA[4], hldB[4];
    f32x4 rA, zA, nA, hA, rB, zB, nB, hB;

    LOADA(0, amgA, ahhA, hldA); MFMAS(amgA, ahhA, rA, zA, nA, hA);
    LOADA(1, amgB, ahhB, hldB); MFMAS(amgB, ahhB, rB, zB, nB, hB); EPI(0, rA, zA, nA, hA, hldA);
    LOADA(2, amgA, ahhA, hldA); MFMAS(amgA, ahhA, rA, zA, nA, hA); EPI(1, rB, zB, nB, hB, hldB);
    LOADA(3, amgB, ahhB, hldB); MFMAS(amgB, ahhB, rB, zB, nB, hB); EPI(2, rA, zA, nA, hA, hldA);
    EPI(3, rB, zB, nB, hB, hldB);

    __syncthreads();
  }
#undef LOADA
#undef MFMAS
#undef EPI
}

// ---------- output head ----------
__global__ __launch_bounds__(256) void k_out(const u16* __restrict__ h, const float* __restrict__ wo, const float* __restrict__ bo, float* __restrict__ out){
  const int wv = threadIdx.x >> 6, ln = threadIdx.x & 63;
  const int n = (blockIdx.x*4 + wv)*4 + (ln >> 4);
  const int kc = (ln & 15)*8;
  uint4 v = *reinterpret_cast<const uint4*>(h + (size_t)n*HD + kc);
  float4 w0 = *reinterpret_cast<const float4*>(wo + kc);
  float4 w1 = *reinterpret_cast<const float4*>(wo + kc + 4);
  float s = b2f(v.x & 0xffffu)*w0.x + b2f(v.x >> 16)*w0.y + b2f(v.y & 0xffffu)*w0.z + b2f(v.y >> 16)*w0.w
          + b2f(v.z & 0xffffu)*w1.x + b2f(v.z >> 16)*w1.y + b2f(v.w & 0xffffu)*w1.z + b2f(v.w >> 16)*w1.w;
  #pragma unroll
  for (int d=1; d<16; d<<=1) s += __shfl_xor(s, d, 16);
  if ((ln & 15) == 0) out[n] = s + bo[0];
}

// ---------- workspace layout ----------
#define AL256(x) ((((size_t)(x)) + 255) & ~(size_t)255)
static const size_t SZ_STATE = (size_t)NN*HD*2;
static const size_t OFF_HA   = 0;                       // h ping buffer
static const size_t OFF_HB   = OFF_HA + SZ_STATE;       // h pong buffer / m buffer
static const size_t OFF_MAGG = OFF_HB + SZ_STATE;
static const size_t OFF_RP   = OFF_MAGG + SZ_STATE;
static const size_t OFF_CUR  = OFF_RP + AL256((size_t)(NN+1)*4);
static const size_t OFF_CNT  = OFF_CUR + (size_t)NN*4;
static const size_t OFF_EXCL = OFF_CNT + (size_t)NN*4;
static const size_t OFF_BSUM = OFF_EXCL + (size_t)NN*4;
static const size_t OFF_CX   = OFF_BSUM + AL256(1024*4);
static const size_t OFF_FLAG = OFF_CX + (size_t)EN*4;
static const size_t OFF_WTIN = OFF_FLAG + 256;
static const size_t OFF_WTE1 = OFF_WTIN + AL256((size_t)IND*HD*2);
static const size_t OFF_WTE2 = OFF_WTE1 + AL256((size_t)HD*HD*2);
static const size_t OFF_WTIH = OFF_WTE2 + AL256((size_t)HD*HD*2);
static const size_t OFF_WTHH = OFF_WTIH + AL256((size_t)HD*3*HD*2);

extern "C" void kernel_launch(void* const* d_in, const int* in_sizes, int n_in,
                              void* d_out, int out_size, void* d_ws, size_t ws_size,
                              hipStream_t stream){
  const float* x    = (const float*)d_in[0];
  const int*   ei   = (const int*)d_in[1];
  const float* W_in = (const float*)d_in[2];  const float* b_in = (const float*)d_in[3];
  const float* W_e1 = (const float*)d_in[4];  const float* b_e1 = (const float*)d_in[5];
  const float* W_e2 = (const float*)d_in[6];  const float* b_e2 = (const float*)d_in[7];
  const float* W_ih = (const float*)d_in[8];  const float* b_ih = (const float*)d_in[9];
  const float* W_hh = (const float*)d_in[10]; const float* b_hh = (const float*)d_in[11];
  const float* W_out= (const float*)d_in[12]; const float* b_out= (const float*)d_in[13];
  float* out = (float*)d_out;

  char* ws = (char*)d_ws;
  u16* hA   = (u16*)(ws + OFF_HA);
  u16* hB   = (u16*)(ws + OFF_HB);
  u16* magg = (u16*)(ws + OFF_MAGG);
  int* rp   = (int*)(ws + OFF_RP);
  int* cur  = (int*)(ws + OFF_CUR);
  int* cnt  = (int*)(ws + OFF_CNT);
  int* excl = (int*)(ws + OFF_EXCL);
  int* bsum = (int*)(ws + OFF_BSUM);
  int* cx   = (int*)(ws + OFF_CX);
  int* flag = (int*)(ws + OFF_FLAG);
  u16* wtin = (u16*)(ws + OFF_WTIN);
  u16* wte1 = (u16*)(ws + OFF_WTE1);
  u16* wte2 = (u16*)(ws + OFF_WTE2);
  u16* wtih = (u16*)(ws + OFF_WTIH);
  u16* wthh = (u16*)(ws + OFF_WTHH);

  hipFuncSetAttribute((const void*)k_edge, hipFuncAttributeMaxDynamicSharedMemorySize, 49152);
  hipFuncSetAttribute((const void*)k_gru,  hipFuncAttributeMaxDynamicSharedMemorySize, 65536);

  hipMemsetAsync(cnt, 0, (size_t)NN*4, stream);

  k_w2bt<<<(IND*HD + 255)/256, 256, 0, stream>>>(W_in, wtin, IND, HD);
  k_w2bt<<<(HD*HD + 255)/256, 256, 0, stream>>>(W_e1, wte1, HD, HD);
  k_w2bt<<<(HD*HD + 255)/256, 256, 0, stream>>>(W_e2, wte2, HD, HD);
  k_w2bt<<<(HD*3*HD + 255)/256, 256, 0, stream>>>(W_ih, wtih, HD, 3*HD);
  k_w2bt<<<(HD*3*HD + 255)/256, 256, 0, stream>>>(W_hh, wthh, HD, 3*HD);

  k_eflag<<<1, 64, 0, stream>>>(ei, flag);
  k_count<<<EN/256, 256, 0, stream>>>(ei, flag, cnt);
  k_scan1<<<NN/256, 256, 0, stream>>>(cnt, excl, bsum);
  k_scan2<<<1, 1024, 0, stream>>>(bsum);
  k_scan3<<<NN/256, 256, 0, stream>>>(excl, bsum, rp, cur);
  k_fill<<<EN/256, 256, 0, stream>>>(ei, flag, cur, cx);

  k_input<<<NN/128, 256, 0, stream>>>(x, wtin, b_in, hA);

  // ping-pong: h state alternates hA -> hB -> hA -> hB; m shares the inactive buffer
  for (int it=0; it<3; ++it){
    u16* hin  = (it & 1) ? hB : hA;
    u16* hout = (it & 1) ? hA : hB;   // also serves as the m buffer this iteration
    k_edge<<<GRID_E, 512, 49152, stream>>>(hin, wte1, b_e1, wte2, b_e2, hout);
    k_agg<<<NN/8, 256, 0, stream>>>(hout, rp, cx, magg);
    k_gru<<<GRID_G, 256, 65536, stream>>>(magg, hin, hout, wtih, b_ih, wthh, b_hh);
  }
  k_out<<<NN/16, 256, 0, stream>>>(hB, W_out, b_out, out);
}